// Round 1
// baseline (433.363 us; speedup 1.0000x reference)
//
#include <hip/hip_runtime.h>
#include <math.h>

typedef unsigned short u16;
typedef unsigned int u32;
typedef __attribute__((ext_vector_type(8))) __bf16 bf16x8;
typedef __attribute__((ext_vector_type(4))) float f32x4;

#define B_ 2
#define N_ 4096
#define DIM_ 1024
#define QK_ 128
#define HID_ 2048
#define M_TOT (B_*N_)   // 8192

__device__ __forceinline__ u16 f2bf(float f) {
  union { float f; u32 u; } v; v.f = f;
  u32 r = v.u + 0x7fffu + ((v.u >> 16) & 1u);
  return (u16)(r >> 16);
}
__device__ __forceinline__ float bf2f(u16 h) {
  union { u32 u; float f; } v; v.u = ((u32)h) << 16;
  return v.f;
}
__device__ __forceinline__ float silu_f(float v) { return v / (1.0f + expf(-v)); }

// ---------------- LayerNorm: x (f32 [8192][1024]) -> normed bf16 ----------------
__global__ __launch_bounds__(256) void ln_kernel(
    const float* __restrict__ x, const float* __restrict__ g,
    const float* __restrict__ b, u16* __restrict__ out) {
  const int row = blockIdx.x;
  const int t = threadIdx.x;
  const float4* xr = (const float4*)(x + (size_t)row * DIM_);
  float4 v = xr[t];
  float s  = v.x + v.y + v.z + v.w;
  float s2 = v.x*v.x + v.y*v.y + v.z*v.z + v.w*v.w;
  #pragma unroll
  for (int o = 32; o > 0; o >>= 1) { s += __shfl_down(s, o); s2 += __shfl_down(s2, o); }
  __shared__ float red[2][4];
  const int wave = t >> 6, lane = t & 63;
  if (lane == 0) { red[0][wave] = s; red[1][wave] = s2; }
  __syncthreads();
  float ts  = red[0][0] + red[0][1] + red[0][2] + red[0][3];
  float ts2 = red[1][0] + red[1][1] + red[1][2] + red[1][3];
  float mu  = ts * (1.0f/(float)DIM_);
  float var = ts2 * (1.0f/(float)DIM_) - mu*mu;
  float rs  = rsqrtf(var + 1e-5f);
  const float4 gg = ((const float4*)g)[t];
  const float4 bb = ((const float4*)b)[t];
  ushort4 w;
  w.x = f2bf((v.x-mu)*rs*gg.x + bb.x);
  w.y = f2bf((v.y-mu)*rs*gg.y + bb.y);
  w.z = f2bf((v.z-mu)*rs*gg.z + bb.z);
  w.w = f2bf((v.w-mu)*rs*gg.w + bb.w);
  ((ushort4*)(out + (size_t)row*DIM_))[t] = w;
}

// ------------- transpose + f32->bf16: in [R][C] f32 -> out [C][R] bf16 -------------
__global__ __launch_bounds__(256) void transpose_k(
    const float* __restrict__ in, u16* __restrict__ out, int R, int C) {
  __shared__ float tile[32][33];
  const int c0 = blockIdx.x * 32, r0 = blockIdx.y * 32;
  const int tx = threadIdx.x & 31, ty = threadIdx.x >> 5;  // 32x8
  #pragma unroll
  for (int i = 0; i < 4; ++i)
    tile[ty + i*8][tx] = in[(size_t)(r0 + ty + i*8) * C + c0 + tx];
  __syncthreads();
  #pragma unroll
  for (int i = 0; i < 4; ++i)
    out[(size_t)(c0 + ty + i*8) * R + r0 + tx] = f2bf(tile[tx][ty + i*8]);
}

// ---------------- generic NT bf16 MFMA GEMM, 128x128 tile, BK=64 ----------------
// C[m][n] = sum_k A[m][k] * BT[n][k]   (both operands K-contiguous, bf16)
enum { EPI_HV, EPI_QK, EPI_S, EPI_PV, EPI_O };

template<int EPI>
__global__ __launch_bounds__(256) void gemm_nt(
    const u16* __restrict__ A, int lda,
    const u16* __restrict__ BT, int ldb, int K,
    void* __restrict__ Cv, void* __restrict__ C2v, int ldc,
    const float* __restrict__ f0, const float* __restrict__ f1,
    const float* __restrict__ f2,
    const u16* __restrict__ hvT, const float* __restrict__ xres)
{
  const int bm = blockIdx.x, bn = blockIdx.y, bz = blockIdx.z;
  if (EPI == EPI_S && bm < bn) return;      // strictly-upper causal tiles: skip
  if (EPI == EPI_S) { A += (size_t)bz*N_*QK_; BT += (size_t)bz*N_*QK_; }
  if (EPI == EPI_PV){ A += (size_t)bz*N_*N_; BT += (size_t)bz*N_; }
  __shared__ __align__(16) u16 lds[2][128*64];   // [0]=A tile [128][64], [1]=BT tile [128][64]
  const int tid = threadIdx.x, wave = tid >> 6, lane = tid & 63;
  const int m0 = bm*128, n0 = bn*128;
  int kmax = K;
  if (EPI == EPI_PV) kmax = min(K, (bm+1)*128);  // causal K bound
  f32x4 acc[4][4] = {};
  const int wr = (wave >> 1)*64, wc = (wave & 1)*64;
  const u16* ga = A  + (size_t)(m0 + (lane>>3))*lda + (lane&7)*8;
  const u16* gb = BT + (size_t)(n0 + (lane>>3))*ldb + (lane&7)*8;

  for (int k0 = 0; k0 < kmax; k0 += 64) {
    #pragma unroll
    for (int t = 0; t < 4; ++t) {
      const int chunk = wave*4 + t;  // 16 chunks of 1KB each per tile
      __builtin_amdgcn_global_load_lds(
          (const __attribute__((address_space(1))) void*)(ga + (size_t)(chunk*8)*lda + k0),
          (__attribute__((address_space(3))) void*)&lds[0][chunk*512], 16, 0, 0);
      __builtin_amdgcn_global_load_lds(
          (const __attribute__((address_space(1))) void*)(gb + (size_t)(chunk*8)*ldb + k0),
          (__attribute__((address_space(3))) void*)&lds[1][chunk*512], 16, 0, 0);
    }
    __syncthreads();
    #pragma unroll
    for (int kk = 0; kk < 64; kk += 32) {
      bf16x8 af[4], bfr[4];
      #pragma unroll
      for (int i = 0; i < 4; ++i) {
        af[i]  = *(const bf16x8*)&lds[0][(wr + i*16 + (lane&15))*64 + kk + (lane>>4)*8];
        bfr[i] = *(const bf16x8*)&lds[1][(wc + i*16 + (lane&15))*64 + kk + (lane>>4)*8];
      }
      #pragma unroll
      for (int i = 0; i < 4; ++i)
        #pragma unroll
        for (int j = 0; j < 4; ++j)
          acc[i][j] = __builtin_amdgcn_mfma_f32_16x16x32_bf16(af[i], bfr[j], acc[i][j], 0, 0, 0);
    }
    __syncthreads();
  }

  const int lr = (lane >> 4)*4, lc = lane & 15;
  #pragma unroll
  for (int i = 0; i < 4; ++i) {
    #pragma unroll
    for (int j = 0; j < 4; ++j) {
      #pragma unroll
      for (int e = 0; e < 4; ++e) {
        const int row = m0 + wr + i*16 + lr + e;
        const int col = n0 + wc + j*16 + lc;
        float v = acc[i][j][e];
        if (EPI == EPI_HV) {
          v = silu_f(v + f0[row]);                       // bias per hv-feature (= C row)
          ((u16*)Cv)[(size_t)row*ldc + col] = f2bf(v);
        } else if (EPI == EPI_QK) {
          float s = silu_f(v + f0[col]);
          float q = (s*f1[col]       + f2[col])       * (1.0f/(float)N_);  // fold 1/n
          float k2 = s*f1[QK_+col]   + f2[QK_+col];
          ((u16*)Cv )[(size_t)row*ldc + col] = f2bf(q);
          ((u16*)C2v)[(size_t)row*ldc + col] = f2bf(k2);
        } else if (EPI == EPI_S) {
          float p = (row >= col && v > 0.0f) ? v*v : 0.0f;  // causal + relu^2
          ((u16*)Cv)[(size_t)bz*N_*N_ + (size_t)row*ldc + col] = f2bf(p);
        } else if (EPI == EPI_PV) {
          float gate = bf2f(hvT[(size_t)(HID_ + col)*M_TOT + (size_t)bz*N_ + row]);
          ((u16*)Cv)[((size_t)bz*N_ + row)*ldc + col] = f2bf(v * gate);
        } else {  // EPI_O
          v += f0[col] + xres[(size_t)row*DIM_ + col];   // bias + residual
          ((float*)Cv)[(size_t)row*ldc + col] = v;
        }
      }
    }
  }
}

// ---------------- host ----------------
extern "C" void kernel_launch(void* const* d_in, const int* in_sizes, int n_in,
                              void* d_out, int out_size, void* d_ws, size_t ws_size,
                              hipStream_t stream) {
  const float* x    = (const float*)d_in[0];
  const float* ln_g = (const float*)d_in[1];
  const float* ln_b = (const float*)d_in[2];
  const float* Wh   = (const float*)d_in[3];
  const float* bh   = (const float*)d_in[4];
  const float* Wqk  = (const float*)d_in[5];
  const float* bqk  = (const float*)d_in[6];
  const float* gamma= (const float*)d_in[7];
  const float* beta = (const float*)d_in[8];
  const float* Wo   = (const float*)d_in[9];
  const float* bo   = (const float*)d_in[10];
  float* out = (float*)d_out;
  char* ws = (char*)d_ws;

  u16* normed = (u16*)(ws + 0);           // 8192x1024    16 MB
  u16* WhT    = (u16*)(ws + 16777216);    // 4096x1024     8 MB
  u16* WqkT   = (u16*)(ws + 25165824);    //  128x1024   256 KB
  u16* WoT    = (u16*)(ws + 25427968);    // 1024x2048     4 MB
  u16* hvT    = (u16*)(ws + 29622272);    // 4096x8192    64 MB  (rows 0..2047=v^T, 2048..4095=gate^T)
  u16* qs     = (u16*)(ws + 96731136);    // 8192x128      2 MB  (q * 1/n)
  u16* kb     = (u16*)(ws + 98828288);    // 8192x128      2 MB
  u16* P      = (u16*)(ws + 100925440);   // 2x4096x4096  64 MB
  u16* a2     = (u16*)(ws + 168034304);   // 8192x2048    32 MB

  ln_kernel<<<M_TOT, 256, 0, stream>>>(x, ln_g, ln_b, normed);
  transpose_k<<<dim3(4096/32, 1024/32), 256, 0, stream>>>(Wh,  WhT,  1024, 4096);
  transpose_k<<<dim3( 128/32, 1024/32), 256, 0, stream>>>(Wqk, WqkT, 1024, 128);
  transpose_k<<<dim3(1024/32, 2048/32), 256, 0, stream>>>(Wo,  WoT,  2048, 1024);

  // hvT = silu(WhT @ normed^T + bh):  M=4096 (features), N=8192 (tokens), K=1024
  gemm_nt<EPI_HV><<<dim3(32, 64), 256, 0, stream>>>(WhT, 1024, normed, 1024, 1024,
      hvT, nullptr, 8192, bh, nullptr, nullptr, nullptr, nullptr);
  // qk = silu(normed @ Wqk + bqk) -> q (scaled), k:  M=8192, N=128, K=1024
  gemm_nt<EPI_QK><<<dim3(64, 1), 256, 0, stream>>>(normed, 1024, WqkT, 1024, 1024,
      qs, kb, 128, bqk, gamma, beta, nullptr, nullptr);
  // P = relu(q_s @ k^T)^2 with causal mask:  per batch M=N=4096, K=128
  gemm_nt<EPI_S><<<dim3(32, 32, 2), 256, 0, stream>>>(qs, 128, kb, 128, 128,
      P, nullptr, 4096, nullptr, nullptr, nullptr, nullptr, nullptr);
  // a2 = (P @ V) * gate:  per batch M=4096, N=2048(hid), K<=4096 causal-bounded
  gemm_nt<EPI_PV><<<dim3(32, 16, 2), 256, 0, stream>>>(P, 4096, hvT, 8192, 4096,
      a2, nullptr, 2048, nullptr, nullptr, nullptr, hvT, nullptr);
  // out = a2 @ Wo + bo + x:  M=8192, N=1024, K=2048
  gemm_nt<EPI_O><<<dim3(64, 8), 256, 0, stream>>>(a2, 2048, WoT, 2048, 2048,
      out, nullptr, 1024, bo, nullptr, nullptr, nullptr, x);
}

// Round 2
// 337.721 us; speedup vs baseline: 1.2832x; 1.2832x over previous
//
#include <hip/hip_runtime.h>
#include <math.h>

typedef unsigned short u16;
typedef unsigned int u32;
typedef __attribute__((ext_vector_type(8))) __bf16 bf16x8;
typedef __attribute__((ext_vector_type(4))) float f32x4;

#define B_ 2
#define N_ 4096
#define DIM_ 1024
#define QK_ 128
#define HID_ 2048
#define M_TOT (B_*N_)   // 8192

__device__ __forceinline__ u16 f2bf(float f) {
  union { float f; u32 u; } v; v.f = f;
  u32 r = v.u + 0x7fffu + ((v.u >> 16) & 1u);
  return (u16)(r >> 16);
}
__device__ __forceinline__ float bf2f(u16 h) {
  union { u32 u; float f; } v; v.u = ((u32)h) << 16;
  return v.f;
}
__device__ __forceinline__ float silu_f(float v) { return v / (1.0f + expf(-v)); }

#define WAIT_VM(n)  asm volatile("s_waitcnt vmcnt(" #n ")" ::: "memory")
#define WAIT_LG0()  asm volatile("s_waitcnt lgkmcnt(0)" ::: "memory")
#define SB0()       __builtin_amdgcn_sched_barrier(0)

// ---------------- LayerNorm: x (f32 [8192][1024]) -> normed bf16 ----------------
__global__ __launch_bounds__(256) void ln_kernel(
    const float* __restrict__ x, const float* __restrict__ g,
    const float* __restrict__ b, u16* __restrict__ out) {
  const int row = blockIdx.x;
  const int t = threadIdx.x;
  const float4* xr = (const float4*)(x + (size_t)row * DIM_);
  float4 v = xr[t];
  float s  = v.x + v.y + v.z + v.w;
  float s2 = v.x*v.x + v.y*v.y + v.z*v.z + v.w*v.w;
  #pragma unroll
  for (int o = 32; o > 0; o >>= 1) { s += __shfl_down(s, o); s2 += __shfl_down(s2, o); }
  __shared__ float red[2][4];
  const int wave = t >> 6, lane = t & 63;
  if (lane == 0) { red[0][wave] = s; red[1][wave] = s2; }
  __syncthreads();
  float ts  = red[0][0] + red[0][1] + red[0][2] + red[0][3];
  float ts2 = red[1][0] + red[1][1] + red[1][2] + red[1][3];
  float mu  = ts * (1.0f/(float)DIM_);
  float var = ts2 * (1.0f/(float)DIM_) - mu*mu;
  float rs  = rsqrtf(var + 1e-5f);
  const float4 gg = ((const float4*)g)[t];
  const float4 bb = ((const float4*)b)[t];
  ushort4 w;
  w.x = f2bf((v.x-mu)*rs*gg.x + bb.x);
  w.y = f2bf((v.y-mu)*rs*gg.y + bb.y);
  w.z = f2bf((v.z-mu)*rs*gg.z + bb.z);
  w.w = f2bf((v.w-mu)*rs*gg.w + bb.w);
  ((ushort4*)(out + (size_t)row*DIM_))[t] = w;
}

// ------------- transpose + f32->bf16: in [R][C] f32 -> out [C][R] bf16 -------------
__global__ __launch_bounds__(256) void transpose_k(
    const float* __restrict__ in, u16* __restrict__ out, int R, int C) {
  __shared__ float tile[32][33];
  const int c0 = blockIdx.x * 32, r0 = blockIdx.y * 32;
  const int tx = threadIdx.x & 31, ty = threadIdx.x >> 5;  // 32x8
  #pragma unroll
  for (int i = 0; i < 4; ++i)
    tile[ty + i*8][tx] = in[(size_t)(r0 + ty + i*8) * C + c0 + tx];
  __syncthreads();
  #pragma unroll
  for (int i = 0; i < 4; ++i)
    out[(size_t)(c0 + ty + i*8) * R + r0 + tx] = f2bf(tile[tx][ty + i*8]);
}

enum { EPI_HV, EPI_QK, EPI_S, EPI_PV, EPI_O };

// ---------------- old 128x128 2-phase kernel — kept for S and QK ----------------
template<int EPI>
__global__ __launch_bounds__(256) void gemm_nt(
    const u16* __restrict__ A, int lda,
    const u16* __restrict__ BT, int ldb, int K,
    void* __restrict__ Cv, void* __restrict__ C2v, int ldc,
    const float* __restrict__ f0, const float* __restrict__ f1,
    const float* __restrict__ f2,
    const u16* __restrict__ hvT, const float* __restrict__ xres)
{
  const int bm = blockIdx.x, bn = blockIdx.y, bz = blockIdx.z;
  if (EPI == EPI_S && bm < bn) return;      // strictly-upper causal tiles: skip
  if (EPI == EPI_S) { A += (size_t)bz*N_*QK_; BT += (size_t)bz*N_*QK_; }
  __shared__ __align__(16) u16 lds[2][128*64];
  const int tid = threadIdx.x, wave = tid >> 6, lane = tid & 63;
  const int m0 = bm*128, n0 = bn*128;
  int kmax = K;
  f32x4 acc[4][4] = {};
  const int wr = (wave >> 1)*64, wc = (wave & 1)*64;
  const u16* ga = A  + (size_t)(m0 + (lane>>3))*lda + (lane&7)*8;
  const u16* gb = BT + (size_t)(n0 + (lane>>3))*ldb + (lane&7)*8;

  for (int k0 = 0; k0 < kmax; k0 += 64) {
    #pragma unroll
    for (int t = 0; t < 4; ++t) {
      const int chunk = wave*4 + t;
      __builtin_amdgcn_global_load_lds(
          (const __attribute__((address_space(1))) void*)(ga + (size_t)(chunk*8)*lda + k0),
          (__attribute__((address_space(3))) void*)&lds[0][chunk*512], 16, 0, 0);
      __builtin_amdgcn_global_load_lds(
          (const __attribute__((address_space(1))) void*)(gb + (size_t)(chunk*8)*ldb + k0),
          (__attribute__((address_space(3))) void*)&lds[1][chunk*512], 16, 0, 0);
    }
    __syncthreads();
    #pragma unroll
    for (int kk = 0; kk < 64; kk += 32) {
      bf16x8 af[4], bfr[4];
      #pragma unroll
      for (int i = 0; i < 4; ++i) {
        af[i]  = *(const bf16x8*)&lds[0][(wr + i*16 + (lane&15))*64 + kk + (lane>>4)*8];
        bfr[i] = *(const bf16x8*)&lds[1][(wc + i*16 + (lane&15))*64 + kk + (lane>>4)*8];
      }
      #pragma unroll
      for (int i = 0; i < 4; ++i)
        #pragma unroll
        for (int j = 0; j < 4; ++j)
          acc[i][j] = __builtin_amdgcn_mfma_f32_16x16x32_bf16(af[i], bfr[j], acc[i][j], 0, 0, 0);
    }
    __syncthreads();
  }

  const int lr = (lane >> 4)*4, lc = lane & 15;
  #pragma unroll
  for (int i = 0; i < 4; ++i) {
    #pragma unroll
    for (int j = 0; j < 4; ++j) {
      #pragma unroll
      for (int e = 0; e < 4; ++e) {
        const int row = m0 + wr + i*16 + lr + e;
        const int col = n0 + wc + j*16 + lc;
        float v = acc[i][j][e];
        if (EPI == EPI_QK) {
          float s = silu_f(v + f0[col]);
          float q = (s*f1[col]       + f2[col])       * (1.0f/(float)N_);
          float k2 = s*f1[QK_+col]   + f2[QK_+col];
          ((u16*)Cv )[(size_t)row*ldc + col] = f2bf(q);
          ((u16*)C2v)[(size_t)row*ldc + col] = f2bf(k2);
        } else if (EPI == EPI_S) {
          float p = (row >= col && v > 0.0f) ? v*v : 0.0f;
          ((u16*)Cv)[(size_t)bz*N_*N_ + (size_t)row*ldc + col] = f2bf(p);
        }
      }
    }
  }
}

// ------------- new 8-wave ring-4 pipelined GEMM: BM x 256 tile, BK=32 -------------
// C[m][n] = sum_k A[m][k]*BT[n][k].  T2 both-sides swizzle, counted vmcnt, setprio.
template<int BM_, int EPI>
__global__ __launch_bounds__(512, 2) void gemm_big(
    const u16* __restrict__ A, int lda,
    const u16* __restrict__ BT, int ldb, int K,
    void* __restrict__ Cv, int ldc,
    const float* __restrict__ f0,
    const u16* __restrict__ hvT, const float* __restrict__ xres)
{
  constexpr int IF   = BM_/32;      // A frags per wave (8 or 4)
  constexpr int APW  = (BM_/16)/8;  // A chunks per wave (2 or 1)
  constexpr int ASZ  = BM_*32;      // u16 per A tile (BM x 32)
  constexpr int BSZ  = 256*32;
  constexpr int SLOT = ASZ + BSZ;
  __shared__ __align__(16) u16 lds[4*SLOT];

  int bm = blockIdx.x;
  const int bn = blockIdx.y, bz = blockIdx.z;
  if constexpr (EPI == EPI_PV) { if (bz) bm = (gridDim.x - 1) - bm; }  // balance causal work
  const int tid = threadIdx.x, wave = tid >> 6, lane = tid & 63;
  const int wm = wave >> 2, wn = wave & 3;
  const int m0 = bm*BM_, n0 = bn*256;

  const u16* Ap = A;  const u16* Bp = BT;
  if constexpr (EPI == EPI_PV) { Ap += (size_t)bz*N_*N_; Bp += (size_t)bz*N_; }

  int kmax = K;
  if constexpr (EPI == EPI_PV) kmax = (bm+1)*BM_;   // causal bound (P zero/unwritten beyond)
  const int nt = kmax >> 5;                          // BK=32 tiles; nt >= 4 for all uses

  f32x4 acc[IF][4] = {};

  auto stage = [&](int t) {
    if (t >= nt) return;
    const int k0 = t*32;
    u16* sA = &lds[(size_t)(t & 3) * SLOT];
    u16* sB = sA + ASZ;
    #pragma unroll
    for (int c = 0; c < APW; ++c) {
      const int ch = wave*APW + c;
      const int R  = ch*16 + (lane >> 2);
      const int q  = (lane & 3) ^ ((R >> 1) & 3);     // pre-swizzled source quad
      const u16* src = Ap + (size_t)(m0 + R)*lda + k0 + q*8;
      __builtin_amdgcn_global_load_lds(
          (const __attribute__((address_space(1))) void*)src,
          (__attribute__((address_space(3))) void*)(sA + ch*512), 16, 0, 0);
    }
    #pragma unroll
    for (int c = 0; c < 2; ++c) {
      const int ch = wave*2 + c;
      const int R  = ch*16 + (lane >> 2);
      const int q  = (lane & 3) ^ ((R >> 1) & 3);
      const u16* src = Bp + (size_t)(n0 + R)*ldb + k0 + q*8;
      __builtin_amdgcn_global_load_lds(
          (const __attribute__((address_space(1))) void*)src,
          (__attribute__((address_space(3))) void*)(sB + ch*512), 16, 0, 0);
    }
  };

  stage(0); stage(1); stage(2);

  // per-thread constant fragment-read offsets (swizzle slot is i-independent)
  const int rA = wm*(BM_/2) + (lane & 15);
  const int rB = wn*64 + (lane & 15);
  const int idxA0 = rA*32 + (((lane >> 4) ^ ((rA >> 1) & 3)) * 8);
  const int idxB0 = rB*32 + (((lane >> 4) ^ ((rB >> 1) & 3)) * 8);

  for (int t = 0; t < nt; ++t) {
    // counted vmcnt: tiles t+1,t+2 may stay in flight (LP loads each)
    if (t + 2 < nt)      { if constexpr (BM_ == 256) { WAIT_VM(8); } else { WAIT_VM(6); } }
    else if (t + 1 < nt) { if constexpr (BM_ == 256) { WAIT_VM(4); } else { WAIT_VM(3); } }
    else                 { WAIT_VM(0); }
    SB0();
    __builtin_amdgcn_s_barrier();
    SB0();
    const u16* sA = &lds[(size_t)(t & 3) * SLOT];
    const u16* sB = sA + ASZ;
    stage(t + 3);   // ring slot (t+3)&3 was last read at tile t-1, before this barrier

    bf16x8 bfr[4], af[IF/2];
    #pragma unroll
    for (int j = 0; j < 4; ++j) bfr[j] = *(const bf16x8*)&sB[idxB0 + j*512];
    #pragma unroll
    for (int i = 0; i < IF/2; ++i) af[i] = *(const bf16x8*)&sA[idxA0 + i*512];
    WAIT_LG0(); SB0();
    __builtin_amdgcn_s_setprio(1);
    #pragma unroll
    for (int i = 0; i < IF/2; ++i)
      #pragma unroll
      for (int j = 0; j < 4; ++j)
        acc[i][j] = __builtin_amdgcn_mfma_f32_16x16x32_bf16(af[i], bfr[j], acc[i][j], 0, 0, 0);
    __builtin_amdgcn_s_setprio(0);

    #pragma unroll
    for (int i = 0; i < IF/2; ++i) af[i] = *(const bf16x8*)&sA[idxA0 + (IF/2 + i)*512];
    WAIT_LG0(); SB0();
    __builtin_amdgcn_s_setprio(1);
    #pragma unroll
    for (int i = 0; i < IF/2; ++i)
      #pragma unroll
      for (int j = 0; j < 4; ++j)
        acc[IF/2 + i][j] = __builtin_amdgcn_mfma_f32_16x16x32_bf16(af[i], bfr[j], acc[IF/2 + i][j], 0, 0, 0);
    __builtin_amdgcn_s_setprio(0);
  }

  const int lr = (lane >> 4)*4, lc = lane & 15;
  #pragma unroll
  for (int i = 0; i < IF; ++i) {
    #pragma unroll
    for (int j = 0; j < 4; ++j) {
      #pragma unroll
      for (int e = 0; e < 4; ++e) {
        const int row = m0 + wm*(BM_/2) + i*16 + lr + e;
        const int col = n0 + wn*64 + j*16 + lc;
        float v = acc[i][j][e];
        if constexpr (EPI == EPI_HV) {
          ((u16*)Cv)[(size_t)row*ldc + col] = f2bf(silu_f(v + f0[row]));
        } else if constexpr (EPI == EPI_PV) {
          float gate = bf2f(hvT[(size_t)(HID_ + col)*M_TOT + (size_t)bz*N_ + row]);
          ((u16*)Cv)[((size_t)bz*N_ + row)*ldc + col] = f2bf(v * gate);
        } else {  // EPI_O
          ((float*)Cv)[(size_t)row*ldc + col] = v + f0[col] + xres[(size_t)row*DIM_ + col];
        }
      }
    }
  }
}

// ---------------- host ----------------
extern "C" void kernel_launch(void* const* d_in, const int* in_sizes, int n_in,
                              void* d_out, int out_size, void* d_ws, size_t ws_size,
                              hipStream_t stream) {
  const float* x    = (const float*)d_in[0];
  const float* ln_g = (const float*)d_in[1];
  const float* ln_b = (const float*)d_in[2];
  const float* Wh   = (const float*)d_in[3];
  const float* bh   = (const float*)d_in[4];
  const float* Wqk  = (const float*)d_in[5];
  const float* bqk  = (const float*)d_in[6];
  const float* gamma= (const float*)d_in[7];
  const float* beta = (const float*)d_in[8];
  const float* Wo   = (const float*)d_in[9];
  const float* bo   = (const float*)d_in[10];
  float* out = (float*)d_out;
  char* ws = (char*)d_ws;

  u16* normed = (u16*)(ws + 0);           // 8192x1024    16 MB
  u16* WhT    = (u16*)(ws + 16777216);    // 4096x1024     8 MB
  u16* WqkT   = (u16*)(ws + 25165824);    //  128x1024   256 KB
  u16* WoT    = (u16*)(ws + 25427968);    // 1024x2048     4 MB
  u16* hvT    = (u16*)(ws + 29622272);    // 4096x8192    64 MB  (rows 0..2047=v^T, 2048..4095=gate^T)
  u16* qs     = (u16*)(ws + 96731136);    // 8192x128      2 MB  (q * 1/n)
  u16* kb     = (u16*)(ws + 98828288);    // 8192x128      2 MB
  u16* P      = (u16*)(ws + 100925440);   // 2x4096x4096  64 MB
  u16* a2     = (u16*)(ws + 168034304);   // 8192x2048    32 MB

  ln_kernel<<<M_TOT, 256, 0, stream>>>(x, ln_g, ln_b, normed);
  transpose_k<<<dim3(4096/32, 1024/32), 256, 0, stream>>>(Wh,  WhT,  1024, 4096);
  transpose_k<<<dim3( 128/32, 1024/32), 256, 0, stream>>>(Wqk, WqkT, 1024, 128);
  transpose_k<<<dim3(1024/32, 2048/32), 256, 0, stream>>>(Wo,  WoT,  2048, 1024);

  // hvT = silu(WhT @ normed^T + bh):  M=4096 (features), N=8192 (tokens), K=1024
  gemm_big<256, EPI_HV><<<dim3(16, 32), 512, 0, stream>>>(WhT, 1024, normed, 1024, 1024,
      hvT, 8192, bh, nullptr, nullptr);
  // qk = silu(normed @ Wqk + bqk) -> q (scaled), k:  M=8192, N=128, K=1024
  gemm_nt<EPI_QK><<<dim3(64, 1), 256, 0, stream>>>(normed, 1024, WqkT, 1024, 1024,
      qs, kb, 128, bqk, gamma, beta, nullptr, nullptr);
  // P = relu(q_s @ k^T)^2 with causal mask:  per batch M=N=4096, K=128
  gemm_nt<EPI_S><<<dim3(32, 32, 2), 256, 0, stream>>>(qs, 128, kb, 128, 128,
      P, nullptr, 4096, nullptr, nullptr, nullptr, nullptr, nullptr);
  // a2 = (P @ V) * gate:  per batch M=4096 (BM=128), N=2048, K causal-bounded
  gemm_big<128, EPI_PV><<<dim3(32, 8, 2), 512, 0, stream>>>(P, 4096, hvT, 8192, 4096,
      a2, 2048, nullptr, hvT, nullptr);
  // out = a2 @ Wo + bo + x:  M=8192 (BM=128), N=1024, K=2048
  gemm_big<128, EPI_O><<<dim3(64, 4), 512, 0, stream>>>(a2, 2048, WoT, 2048, 2048,
      out, 1024, bo, nullptr, x);
}